// Round 5
// baseline (493.235 us; speedup 1.0000x reference)
//
#include <hip/hip_runtime.h>

// EMAttention2d on MI355X — v5: A-resident GEMM (K=512 fits LDS) for stem and
// head; B streamed from L2 in BK=32 chunks with counted vmcnt; BN stats fused
// into head epilogue. B=16, C=512, N=4096, K=64, 3 EM iters.
// mu_b = colnorm_c(yf^T @ z)  (zn normalization cancels under column L2 norm).

typedef _Float16 half_t;
typedef _Float16 half4 __attribute__((ext_vector_type(4)));
typedef _Float16 half8 __attribute__((ext_vector_type(8)));
typedef float f32x4 __attribute__((ext_vector_type(4)));

#define GLD_LDS(gp, lp) __builtin_amdgcn_global_load_lds( \
    (const __attribute__((address_space(1))) void*)(gp),  \
    (__attribute__((address_space(3))) void*)(lp), 16, 0, 0)

#define SBAR __builtin_amdgcn_sched_barrier(0)
#define RAWBAR do { SBAR; __builtin_amdgcn_s_barrier(); SBAR; } while (0)

template <int L> __device__ __forceinline__ void vmwait() {
  if constexpr (L == 8) asm volatile("s_waitcnt vmcnt(8)" ::: "memory");
  else if constexpr (L == 6) asm volatile("s_waitcnt vmcnt(6)" ::: "memory");
  else if constexpr (L == 4) asm volatile("s_waitcnt vmcnt(4)" ::: "memory");
  else asm volatile("s_waitcnt vmcnt(0)" ::: "memory");
}

constexpr int CB = 16;       // batch
constexpr int CC = 512;      // channels
constexpr int CN = 4096;     // H*W
constexpr int CKK = 64;      // codebook size K
constexpr long MALL = (long)CB * CN;   // 65536

__device__ inline int swz8(int bid, int n) {   // bijective (n % 8 == 0)
  return (bid & 7) * (n >> 3) + (bid >> 3);
}

// ---------------------------------------------------------------------------
// K0: convert weights to fp16; init per-batch muT (K,C) and mu_ck (C,K).
__global__ __launch_bounds__(256) void prep(
    const float* __restrict__ stem_w, const float* __restrict__ head_w,
    const float* __restrict__ mu,
    half_t* __restrict__ swh, half_t* __restrict__ hwh,
    half_t* __restrict__ muT, half_t* __restrict__ muck)
{
  int i = blockIdx.x * 256 + threadIdx.x;   // grid covers C*C = 262144
  swh[i] = (half_t)stem_w[i];
  hwh[i] = (half_t)head_w[i];
  if (i < CC * CKK) {
    int c = i >> 6, k = i & 63;
    half_t v = (half_t)mu[i];               // mu is (C,K) row-major
    for (int b = 0; b < CB; ++b) {
      muT[(long)b * CKK * CC + (long)k * CC + c] = v;
      muck[(long)b * CC * CKK + i] = v;
    }
  }
}

// ---------------------------------------------------------------------------
// x (B,C,N) fp32 -> xT (B,N,C) fp16.
__global__ __launch_bounds__(256) void xpose(
    const float* __restrict__ in, half_t* __restrict__ outT)
{
  __shared__ half_t t[64][65];
  const int s0 = blockIdx.x * 64, r0 = blockIdx.y * 64;   // s: N, r: C
  const long bz = blockIdx.z;
  const float* ib = in + bz * (long)CC * CN;
  half_t* ob = outT + bz * (long)CC * CN;
  const int tid = threadIdx.x, cl = tid & 63, rw = tid >> 6;
#pragma unroll
  for (int it = 0; it < 16; ++it) {
    int r = it * 4 + rw;
    t[cl][r] = (half_t)ib[(long)(r0 + r) * CN + s0 + cl];
  }
  __syncthreads();
#pragma unroll
  for (int it = 0; it < 16; ++it) {
    int s = it * 4 + rw;
    ob[(long)(s0 + s) * CC + r0 + cl] = t[s][cl];
  }
}

// ---------------------------------------------------------------------------
// A-resident GEMM: D[m][o] = sum_c A[m][c] * Bw[o][c] + bias[o], M=65536,
// O=C=512, K=C=512. Per block: 64 A-rows resident in LDS (64 KB, staged once),
// Bw streamed in 16 BK=32 chunks (dbuf 2x32 KB, counted vmcnt(4)).
// 512 threads / 8 waves; wave w owns output cols [w*64, w*64+64).
// MODE bit1: relu. EPI bit0: Co row-major (M,512). EPI bit1: CoT (B,512,4096).
// STATS: fused per-channel sum/sumsq atomics (pre-BN h values).
template <int MODE, int EPI, bool STATS>
__global__ __launch_bounds__(512, 1) void gemm_ares(
    const half_t* __restrict__ A, const half_t* __restrict__ Bw,
    const float* __restrict__ bias,
    half_t* __restrict__ Co, half_t* __restrict__ CoT,
    float* __restrict__ stats)
{
  __shared__ __align__(16) half_t lA[64 * 512];     // 64 KiB, XOR-swizzled
  __shared__ __align__(16) half_t lB[2][512 * 32];  // 2 x 32 KiB, swizzled
  const int tid = threadIdx.x, wid = tid >> 6, lane = tid & 63;
  const int g = lane >> 4;                 // k-slice group 0..3
  const long row0 = (long)blockIdx.x * 64;

  // stage A: inst r writes LDS row r linearly; source chunk pre-XOR'd so
  // LDS[r][d] = A[r][(d ^ (r&7))*8 ..]   (both-sides swizzle, rule #21)
  {
#pragma unroll
    for (int q = 0; q < 8; ++q) {
      const int r = q * 8 + wid;
      const int schunk = lane ^ (r & 7);
      GLD_LDS(A + (row0 + r) * 512 + schunk * 8, &lA[r * 512]);
    }
  }
  auto stageB = [&](int s, int b) {
#pragma unroll
    for (int q = 0; q < 4; ++q) {
      const int t = wid * 4 + q;                  // 16-row group
      const int o = t * 16 + (lane >> 2);
      const int cg = (lane & 3) ^ ((o >> 1) & 3); // source 16B chunk
      GLD_LDS(Bw + (long)o * 512 + s * 32 + cg * 8, &lB[b][t * 512]);
    }
  };

  f32x4 acc[4][4];
#pragma unroll
  for (int i = 0; i < 4; ++i)
#pragma unroll
    for (int j = 0; j < 4; ++j) acc[i][j] = f32x4{0.f, 0.f, 0.f, 0.f};

  stageB(0, 0);
  stageB(1, 1);
  vmwait<4>();               // A (8) + B0 (4) complete; B1 in flight
  RAWBAR;

  for (int s = 0; s < 16; ++s) {
    const half_t* bb = &lB[s & 1][0];
    half8 af[4], bf[4];
#pragma unroll
    for (int i = 0; i < 4; ++i) {
      const int mr = i * 16 + (lane & 15);
      const int c8 = (s * 4 + g) ^ (mr & 7);
      af[i] = *(const half8*)&lA[mr * 512 + c8 * 8];
    }
#pragma unroll
    for (int j = 0; j < 4; ++j) {
      const int orr = wid * 64 + j * 16 + (lane & 15);
      const int cg = g ^ ((orr >> 1) & 3);
      bf[j] = *(const half8*)&bb[orr * 32 + cg * 8];
    }
    __builtin_amdgcn_s_setprio(1);
#pragma unroll
    for (int i = 0; i < 4; ++i)
#pragma unroll
      for (int j = 0; j < 4; ++j)
        acc[i][j] = __builtin_amdgcn_mfma_f32_16x16x32_f16(af[i], bf[j],
                                                           acc[i][j], 0, 0, 0);
    __builtin_amdgcn_s_setprio(0);
    RAWBAR;                          // all waves done reading lB[s&1]
    if (s + 2 < 16) { stageB(s + 2, s & 1); vmwait<4>(); }
    else            { vmwait<0>(); }
    RAWBAR;                          // next buffer fully staged
  }

  // Epilogue via LDS (reuse lB as ep[o][m], 512x64 halfs, XOR-swizzled).
  half_t* ep = &lB[0][0];
#pragma unroll
  for (int j = 0; j < 4; ++j) {
    const int o = wid * 64 + j * 16 + (lane & 15);
    const float bv = bias[o];
    float s1 = 0.f, s2 = 0.f;
#pragma unroll
    for (int i = 0; i < 4; ++i) {
      const int mbase = i * 16 + g * 4;
      half4 h;
#pragma unroll
      for (int r = 0; r < 4; ++r) {
        float v = acc[i][j][r] + bv;
        if constexpr (MODE & 2) v = fmaxf(v, 0.f);
        if constexpr (STATS) { s1 += v; s2 += v * v; }
        h[r] = (half_t)v;
      }
      const int mc = (mbase >> 3) ^ (o & 7);
      *(half4*)&ep[o * 64 + mc * 8 + (mbase & 7)] = h;
    }
    if constexpr (STATS) {
      s1 += __shfl_xor(s1, 16); s1 += __shfl_xor(s1, 32);
      s2 += __shfl_xor(s2, 16); s2 += __shfl_xor(s2, 32);
      if (lane < 16) {
        atomicAdd(&stats[o], s1);
        atomicAdd(&stats[CC + o], s2);
      }
    }
  }
  __syncthreads();
  const long b = row0 >> 12, nbase = row0 & 4095;
  if constexpr (EPI & 1) {           // row-major (m, o-contig)
#pragma unroll
    for (int p = 0; p < 8; ++p) {
      const int q = p * 512 + tid;
      const int m = q >> 6, ch = q & 63;
      half8 v;
#pragma unroll
      for (int e = 0; e < 8; ++e) {
        const int o = ch * 8 + e;
        const int mc = (m >> 3) ^ (o & 7);
        v[e] = ep[o * 64 + mc * 8 + (m & 7)];
      }
      *(half8*)&Co[(row0 + m) * 512 + ch * 8] = v;
    }
  }
  if constexpr (EPI & 2) {           // transposed (B, o, 4096)
#pragma unroll
    for (int p = 0; p < 8; ++p) {
      const int q = p * 512 + tid;
      const int o = q >> 3, mc = q & 7;
      const int mcs = mc ^ (o & 7);
      half8 v = *(const half8*)&ep[o * 64 + mcs * 8];
      *(half8*)&CoT[(b * CC + o) * 4096 + nbase + mc * 8] = v;
    }
  }
}

// ---------------------------------------------------------------------------
// Generic fp16 GEMM, A@B^T form (v4 pipeline): counted-vmcnt dbuf + swizzle.
// Used for the mu-update (atomic split-K) and y2 GEMMs.
// MODE bit0: +bias; bit1: relu; bit2: atomic fp32 accumulate into Cacc.
// EPI bit0: LDS epilogue row-major write.
template <int BM, int BN, int MODE, int EPI, bool SWZ>
__global__ __launch_bounds__(256) void gemm_abt(
    const half_t* __restrict__ A, const half_t* __restrict__ Bm,
    half_t* __restrict__ Co, half_t* __restrict__ CoT,
    float* __restrict__ Cacc, const float* __restrict__ bias,
    int M, int Nn, int Kk, int ksplit, long sA, long sB, long sC)
{
  constexpr int FM = BM / 32, FN = BN / 32;
  constexpr int HB = (BM + BN) * 64;                  // halfs per buffer
  constexpr int LCNT = (BM / 8) / 4 + (BN / 8) / 4;   // stage loads per wave
  constexpr int STG = 2 * HB;
  constexpr int EPS = (EPI != 0) ? BN * (BM + 4) : 0;
  constexpr int TOT = STG > EPS ? STG : EPS;
  __shared__ __align__(16) half_t smem[TOT];

  const int tid = threadIdx.x, wid = tid >> 6, lane = tid & 63;
  int bid = blockIdx.x;
  if constexpr (SWZ) bid = swz8(bid, gridDim.x);
  const int tilesN = Nn / BN;
  const int tm = bid / tilesN, tn = bid % tilesN;
  const long bz = blockIdx.z;
  const half_t* Ab = A + bz * sA + (long)tm * BM * Kk;
  const half_t* Bb = Bm + bz * sB + (long)tn * BN * Kk;
  const int ksteps = Kk >> 6;
  const int per = ksteps / ksplit;
  const int ks0 = blockIdx.y * per, ks1 = ks0 + per;
  const int wr = wid >> 1, wc = wid & 1;

  const int r8 = lane >> 3;                 // row-within-chunk 0..7
  const int gcs = ((lane & 7) ^ r8) * 8;    // pre-swizzled source col (halfs)

  auto stage = [&](int ks, int buf) {
    half_t* dA = smem + buf * HB;
    half_t* dB = dA + BM * 64;
    const half_t* ga = Ab + (long)ks * 64;
#pragma unroll
    for (int c = wid; c < BM / 8; c += 4)
      GLD_LDS(ga + (long)(c * 8 + r8) * Kk + gcs, &dA[c * 512]);
    const half_t* gb = Bb + (long)ks * 64;
#pragma unroll
    for (int c = wid; c < BN / 8; c += 4)
      GLD_LDS(gb + (long)(c * 8 + r8) * Kk + gcs, &dB[c * 512]);
  };

  f32x4 acc[FM][FN];
#pragma unroll
  for (int i = 0; i < FM; ++i)
#pragma unroll
    for (int j = 0; j < FN; ++j) acc[i][j] = f32x4{0.f, 0.f, 0.f, 0.f};

  stage(ks0, 0);
  if (ks0 + 1 < ks1) { stage(ks0 + 1, 1); vmwait<LCNT>(); }
  else               { vmwait<0>(); }
  RAWBAR;

  int cur = 0;
  for (int ks = ks0; ks < ks1; ++ks) {
    const half_t* lA = smem + cur * HB;
    const half_t* lB = lA + BM * 64;
#pragma unroll
    for (int kk = 0; kk < 2; ++kk) {
      half8 af[FM], bfr[FN];
      const int cg = kk * 4 + (lane >> 4);      // col8 within row
#pragma unroll
      for (int i = 0; i < FM; ++i) {
        const int rA = wr * (BM / 2) + i * 16 + (lane & 15);
        af[i] = *(const half8*)&lA[rA * 64 + ((cg ^ (rA & 7)) << 3)];
      }
#pragma unroll
      for (int j = 0; j < FN; ++j) {
        const int rB = wc * (BN / 2) + j * 16 + (lane & 15);
        bfr[j] = *(const half8*)&lB[rB * 64 + ((cg ^ (rB & 7)) << 3)];
      }
      __builtin_amdgcn_s_setprio(1);
#pragma unroll
      for (int i = 0; i < FM; ++i)
#pragma unroll
        for (int j = 0; j < FN; ++j)
          acc[i][j] = __builtin_amdgcn_mfma_f32_16x16x32_f16(af[i], bfr[j],
                                                             acc[i][j], 0, 0, 0);
      __builtin_amdgcn_s_setprio(0);
    }
    RAWBAR;
    const bool more = (ks + 2 < ks1);
    if (more) { stage(ks + 2, cur); vmwait<LCNT>(); }
    else      { vmwait<0>(); }
    RAWBAR;
    cur ^= 1;
  }

  if constexpr (EPI != 0) {
    static_assert(BM == 128 && BN == 128, "LDS epilogue assumes 128x128");
    constexpr int PIT = BM + 4;
    half_t* ep = smem;
#pragma unroll
    for (int j = 0; j < FN; ++j) {
      const int nl = wc * 64 + j * 16 + (lane & 15);
      float bv = 0.f;
      if constexpr (MODE & 1) bv = bias[tn * BN + nl];
#pragma unroll
      for (int i = 0; i < FM; ++i) {
        const int ml = wr * 64 + i * 16 + ((lane >> 4) << 2);
        half4 h;
#pragma unroll
        for (int r = 0; r < 4; ++r) {
          float v = acc[i][j][r] + bv;
          if constexpr (MODE & 2) v = fmaxf(v, 0.f);
          h[r] = (half_t)v;
        }
        *(half4*)&ep[nl * PIT + ml] = h;
      }
    }
    __syncthreads();
    const long rowbase = (long)tm * BM;
    if constexpr (EPI & 1) {
#pragma unroll
      for (int s = 0; s < 8; ++s) {
        const int q = tid + 256 * s;
        const int m = q & 127, cc = q >> 7;
        half8 v;
#pragma unroll
        for (int e = 0; e < 8; ++e) v[e] = ep[(cc * 8 + e) * PIT + m];
        *(half8*)&Co[bz * sC + (rowbase + m) * Nn + tn * BN + cc * 8] = v;
      }
    }
  } else {
#pragma unroll
    for (int j = 0; j < FN; ++j) {
      const int n = tn * BN + wc * (BN / 2) + j * 16 + (lane & 15);
      float bv = 0.f;
      if constexpr (MODE & 1) bv = bias[n];
#pragma unroll
      for (int i = 0; i < FM; ++i) {
        const int mbase = tm * BM + wr * (BM / 2) + i * 16 + ((lane >> 4) << 2);
#pragma unroll
        for (int r = 0; r < 4; ++r) {
          const long idx = bz * sC + (long)(mbase + r) * Nn + n;
          if constexpr ((MODE & 4) != 0) {
            atomicAdd(&Cacc[idx], acc[i][j][r]);
          } else {
            float v = acc[i][j][r] + bv;
            if constexpr ((MODE & 2) != 0) v = fmaxf(v, 0.f);
            Co[idx] = (half_t)v;
          }
        }
      }
    }
  }
}

// ---------------------------------------------------------------------------
// K3: S = Yf @ muT^T (128 rows x 64 cols per block), in-register rowwise
// softmax, writes zT (K,N) always, z (N,K) when zp != nullptr (final iter).
__global__ __launch_bounds__(256) void s_softmax(
    const half_t* __restrict__ Yf, const half_t* __restrict__ muT,
    half_t* __restrict__ zp, half_t* __restrict__ zT)
{
  constexpr int HB = (128 + 64) * 64;     // halfs per staging buffer
  __shared__ __align__(16) union {
    half_t st[2 * HB];                    // 48 KiB staging (dbuf)
    half_t zh[128 * 68];                  // epilogue z tile
  } sm;
  const int tid = threadIdx.x, wid = tid >> 6, lane = tid & 63;
  const int tm = blockIdx.x;
  const long bz = blockIdx.z;
  const half_t* Ab = Yf + bz * (long)CN * CC + (long)tm * 128 * CC;
  const half_t* Bb = muT + bz * (long)CKK * CC;

  const int r8 = lane >> 3;
  const int gcs = ((lane & 7) ^ r8) * 8;

  auto stage = [&](int ks, int buf) {
    half_t* dA = sm.st + buf * HB;
    half_t* dB = dA + 128 * 64;
    const half_t* ga = Ab + (long)ks * 64;
#pragma unroll
    for (int c = wid; c < 16; c += 4)
      GLD_LDS(ga + (long)(c * 8 + r8) * CC + gcs, &dA[c * 512]);
    const half_t* gb = Bb + (long)ks * 64;
#pragma unroll
    for (int c = wid; c < 8; c += 4)
      GLD_LDS(gb + (long)(c * 8 + r8) * CC + gcs, &dB[c * 512]);
  };

  f32x4 acc[2][4];
#pragma unroll
  for (int i = 0; i < 2; ++i)
#pragma unroll
    for (int j = 0; j < 4; ++j) acc[i][j] = f32x4{0.f, 0.f, 0.f, 0.f};

  stage(0, 0);
  stage(1, 1);
  vmwait<6>();
  RAWBAR;
  int cur = 0;
  for (int ks = 0; ks < 8; ++ks) {   // Kk = 512
    const half_t* lA = sm.st + cur * HB;
    const half_t* lB = lA + 128 * 64;
#pragma unroll
    for (int kk = 0; kk < 2; ++kk) {
      half8 af[2], bfr[4];
      const int cg = kk * 4 + (lane >> 4);
#pragma unroll
      for (int i = 0; i < 2; ++i) {
        const int rA = wid * 32 + i * 16 + (lane & 15);
        af[i] = *(const half8*)&lA[rA * 64 + ((cg ^ (rA & 7)) << 3)];
      }
#pragma unroll
      for (int j = 0; j < 4; ++j) {
        const int rB = j * 16 + (lane & 15);
        bfr[j] = *(const half8*)&lB[rB * 64 + ((cg ^ (rB & 7)) << 3)];
      }
      __builtin_amdgcn_s_setprio(1);
#pragma unroll
      for (int i = 0; i < 2; ++i)
#pragma unroll
        for (int j = 0; j < 4; ++j)
          acc[i][j] = __builtin_amdgcn_mfma_f32_16x16x32_f16(af[i], bfr[j],
                                                             acc[i][j], 0, 0, 0);
      __builtin_amdgcn_s_setprio(0);
    }
    RAWBAR;
    const bool more = (ks + 2 < 8);
    if (more) { stage(ks + 2, cur); vmwait<6>(); }
    else      { vmwait<0>(); }
    RAWBAR;
    cur ^= 1;
  }

  // In-register softmax over 64 cols per row.
#pragma unroll
  for (int i = 0; i < 2; ++i)
#pragma unroll
    for (int r = 0; r < 4; ++r) {
      float mx = fmaxf(fmaxf(acc[i][0][r], acc[i][1][r]),
                       fmaxf(acc[i][2][r], acc[i][3][r]));
#pragma unroll
      for (int m = 1; m < 16; m <<= 1) mx = fmaxf(mx, __shfl_xor(mx, m));
      float p[4], s = 0.f;
#pragma unroll
      for (int j = 0; j < 4; ++j) { p[j] = __expf(acc[i][j][r] - mx); s += p[j]; }
#pragma unroll
      for (int m = 1; m < 16; m <<= 1) s += __shfl_xor(s, m);
      const float inv = 1.f / s;
#pragma unroll
      for (int j = 0; j < 4; ++j) acc[i][j][r] = p[j] * inv;
    }

#pragma unroll
  for (int i = 0; i < 2; ++i)
#pragma unroll
    for (int j = 0; j < 4; ++j)
#pragma unroll
      for (int r = 0; r < 4; ++r) {
        const int row = wid * 32 + i * 16 + ((lane >> 4) << 2) + r;
        const int col = j * 16 + (lane & 15);
        sm.zh[row * 68 + col] = (half_t)acc[i][j][r];
      }
  __syncthreads();
  if (zp) { // z (N,K): rows n, contiguous k  (final iter only)
    const int nl = tid >> 1, seg = tid & 1;
    const long base = bz * (long)CN * CKK + (long)(tm * 128 + nl) * CKK + seg * 32;
#pragma unroll
    for (int g = 0; g < 4; ++g) {
      half8 v;
#pragma unroll
      for (int e = 0; e < 8; ++e) v[e] = sm.zh[nl * 68 + seg * 32 + g * 8 + e];
      *(half8*)&zp[base + g * 8] = v;
    }
  }
  { // zT (K,N): rows k, contiguous n
    const int k = tid >> 2, seg = tid & 3;
    const long base = bz * (long)CKK * CN + (long)k * CN + tm * 128 + seg * 32;
#pragma unroll
    for (int g = 0; g < 4; ++g) {
      half8 v;
#pragma unroll
      for (int e = 0; e < 8; ++e) v[e] = sm.zh[(seg * 32 + g * 8 + e) * 68 + k];
      *(half8*)&zT[base + g * 8] = v;
    }
  }
}

// ---------------------------------------------------------------------------
// mu = R / max(||R||_c, 1e-12) per (b,k); write muT (K,C) and mu_ck (C,K).
__global__ __launch_bounds__(64) void mu_norm(
    const float* __restrict__ acc, half_t* __restrict__ muT, half_t* __restrict__ muck)
{
  const int bk = blockIdx.x;           // b*64 + k
  const int b = bk >> 6, k = bk & 63;
  const float* row = acc + (long)bk * CC;
  const int t = threadIdx.x;
  float v[8]; float s = 0.f;
#pragma unroll
  for (int e = 0; e < 8; ++e) { v[e] = row[t * 8 + e]; s += v[e] * v[e]; }
#pragma unroll
  for (int m = 1; m < 64; m <<= 1) s += __shfl_xor(s, m);
  const float inv = 1.f / fmaxf(sqrtf(s), 1e-12f);
  half8 o;
#pragma unroll
  for (int e = 0; e < 8; ++e) o[e] = (half_t)(v[e] * inv);
  *(half8*)&muT[(long)bk * CC + t * 8] = o;
  half_t* mc = muck + (long)b * CC * CKK;
#pragma unroll
  for (int e = 0; e < 8; ++e) mc[(long)(t * 8 + e) * CKK + k] = o[e];
}

// ---------------------------------------------------------------------------
__global__ void bn_param(const float* __restrict__ stats,
                         const float* __restrict__ gamma, const float* __restrict__ beta,
                         float* __restrict__ scsh)
{
  const int c = threadIdx.x;
  const float cnt = 1.f / 65536.f;
  const float mean = stats[c] * cnt;
  const float var = stats[CC + c] * cnt - mean * mean;
  const float sc = gamma[c] * rsqrtf(var + 1e-5f);
  scsh[c] = sc;
  scsh[CC + c] = beta[c] - mean * sc;
}

// ---------------------------------------------------------------------------
// out(B,C,N) = relu( hcn*sc + sh + x ), pure elementwise (hcn already (C,N)).
__global__ __launch_bounds__(256) void bn_final2(
    const half_t* __restrict__ hcn, const float* __restrict__ x,
    const float* __restrict__ scsh, float* __restrict__ out)
{
  const long i8 = (long)blockIdx.x * 256 + threadIdx.x;   // 8-elem chunk id
  const int c = (int)((i8 >> 9) & 511);
  const float sc = scsh[c], sh = scsh[CC + c];
  half8 h = *(const half8*)&hcn[i8 * 8];
  f32x4 x0 = *(const f32x4*)&x[i8 * 8];
  f32x4 x1 = *(const f32x4*)&x[i8 * 8 + 4];
  f32x4 o0, o1;
#pragma unroll
  for (int e = 0; e < 4; ++e) o0[e] = fmaxf((float)h[e] * sc + sh + x0[e], 0.f);
#pragma unroll
  for (int e = 0; e < 4; ++e) o1[e] = fmaxf((float)h[4 + e] * sc + sh + x1[e], 0.f);
  *(f32x4*)&out[i8 * 8] = o0;
  *(f32x4*)&out[i8 * 8 + 4] = o1;
}

// ---------------------------------------------------------------------------
extern "C" void kernel_launch(void* const* d_in, const int* in_sizes, int n_in,
                              void* d_out, int out_size, void* d_ws, size_t ws_size,
                              hipStream_t stream)
{
  const float* x      = (const float*)d_in[0];
  const float* mu     = (const float*)d_in[1];
  const float* stem_w = (const float*)d_in[2];
  const float* stem_b = (const float*)d_in[3];
  const float* head_w = (const float*)d_in[4];
  const float* head_b = (const float*)d_in[5];
  const float* bn_g   = (const float*)d_in[6];
  const float* bn_b   = (const float*)d_in[7];
  float* out = (float*)d_out;

  const size_t NEED = 214ull << 20;
  if (ws_size < NEED) {
    hipMemsetAsync(d_out, 0, (size_t)out_size * 4, stream);
    return;
  }
  char* ws = (char*)d_ws;
  const long MB = 1 << 20;
  half_t* xT   = (half_t*)(ws);              // 64 MiB ; reused as y2f
  half_t* Yf   = (half_t*)(ws + 64 * MB);    // 64 MiB ; reused as hcn
  half_t* ycn  = (half_t*)(ws + 128 * MB);   // 64 MiB
  half_t* z    = (half_t*)(ws + 192 * MB);   // 8 MiB
  half_t* zT   = (half_t*)(ws + 200 * MB);   // 8 MiB
  half_t* muT  = (half_t*)(ws + 208 * MB);   // 1 MiB
  half_t* muck = (half_t*)(ws + 209 * MB);   // 1 MiB
  float* muacc = (float*)(ws + 210 * MB);    // 2 MiB
  half_t* swh  = (half_t*)(ws + 212 * MB);
  half_t* hwh  = (half_t*)(ws + 212 * MB + 512 * 1024);
  float* stats = (float*)(ws + 213 * MB);
  float* scsh  = (float*)(ws + 213 * MB + 8 * 1024);
  half_t* y2f = xT;    // xT dead after stem
  half_t* hcn = Yf;    // Yf dead after final softmax

  prep<<<1024, 256, 0, stream>>>(stem_w, head_w, mu, swh, hwh, muT, muck);
  // xT (B,N,C) <- x (B,C,N)
  xpose<<<dim3(64, 8, 16), 256, 0, stream>>>(x, xT);
  // stem (A-resident): Yf (B*N,C) + ycn (B,C,N) = xT @ stem_w^T + stem_b
  gemm_ares<1, 3, false><<<1024, 512, 0, stream>>>(
      xT, swh, stem_b, Yf, ycn, nullptr);

  for (int it = 0; it < 3; ++it) {
    s_softmax<<<dim3(32, 1, 16), 256, 0, stream>>>(
        Yf, muT, (it == 2) ? z : nullptr, zT);
    hipMemsetAsync(muacc, 0, (size_t)CB * CKK * CC * 4, stream);
    // mu_raw^T (K,C) = zT @ ycn^T (reduction over n, split 4, fp32 atomics)
    gemm_abt<64, 128, 4, 0, false><<<dim3(4, 4, 16), 256, 0, stream>>>(
        zT, ycn, nullptr, nullptr, muacc, nullptr, CKK, CC, CN, 4,
        (long)CKK * CN, (long)CC * CN, (long)CKK * CC);
    mu_norm<<<CB * CKK, 64, 0, stream>>>(muacc, muT, muck);
  }
  // y2f (B,N,C) = relu(z @ mu_ck^T)
  gemm_abt<128, 128, 2, 1, true><<<dim3(128, 1, 16), 256, 0, stream>>>(
      z, muck, y2f, nullptr, nullptr, nullptr, CN, CC, CKK, 1,
      (long)CN * CKK, (long)CC * CKK, (long)CN * CC);
  // head (A-resident, fused BN stats): hcn (B,C,N) = y2f @ head_w^T + head_b
  hipMemsetAsync(stats, 0, 2 * CC * sizeof(float), stream);
  gemm_ares<1, 2, true><<<1024, 512, 0, stream>>>(
      y2f, hwh, head_b, nullptr, hcn, stats);

  bn_param<<<1, 512, 0, stream>>>(stats, bn_g, bn_b, scsh);
  bn_final2<<<16384, 256, 0, stream>>>(hcn, x, scsh, out);
}

// Round 6
// 400.610 us; speedup vs baseline: 1.2312x; 1.2312x over previous
//
#include <hip/hip_runtime.h>

// EMAttention2d on MI355X — v6: v4 pipeline + xpose fused into stem (stem reads
// fp32 x directly, reg-staged transpose+convert into the swizzled LDS A-tile).
// B=16, C=512, N=4096, K=64, 3 EM iters.
// mu_b = colnorm_c(yf^T @ z)  (zn normalization cancels under column L2 norm).

typedef _Float16 half_t;
typedef _Float16 half4 __attribute__((ext_vector_type(4)));
typedef _Float16 half8 __attribute__((ext_vector_type(8)));
typedef float f32x4 __attribute__((ext_vector_type(4)));

#define GLD_LDS(gp, lp) __builtin_amdgcn_global_load_lds( \
    (const __attribute__((address_space(1))) void*)(gp),  \
    (__attribute__((address_space(3))) void*)(lp), 16, 0, 0)

#define SBAR __builtin_amdgcn_sched_barrier(0)
#define RAWBAR do { SBAR; __builtin_amdgcn_s_barrier(); SBAR; } while (0)
#define LGKM0 do { asm volatile("s_waitcnt lgkmcnt(0)" ::: "memory"); SBAR; } while (0)

template <int L> __device__ __forceinline__ void vmwait() {
  if constexpr (L == 8) asm volatile("s_waitcnt vmcnt(8)" ::: "memory");
  else if constexpr (L == 6) asm volatile("s_waitcnt vmcnt(6)" ::: "memory");
  else if constexpr (L == 4) asm volatile("s_waitcnt vmcnt(4)" ::: "memory");
  else asm volatile("s_waitcnt vmcnt(0)" ::: "memory");
}

constexpr int CB = 16;       // batch
constexpr int CC = 512;      // channels
constexpr int CN = 4096;     // H*W
constexpr int CKK = 64;      // codebook size K
constexpr long MALL = (long)CB * CN;   // 65536

__device__ inline int swz8(int bid, int n) {   // bijective (n % 8 == 0)
  return (bid & 7) * (n >> 3) + (bid >> 3);
}

// ---------------------------------------------------------------------------
// K0: convert weights to fp16; init per-batch muT (K,C) and mu_ck (C,K).
__global__ __launch_bounds__(256) void prep(
    const float* __restrict__ stem_w, const float* __restrict__ head_w,
    const float* __restrict__ mu,
    half_t* __restrict__ swh, half_t* __restrict__ hwh,
    half_t* __restrict__ muT, half_t* __restrict__ muck)
{
  int i = blockIdx.x * 256 + threadIdx.x;   // grid covers C*C = 262144
  swh[i] = (half_t)stem_w[i];
  hwh[i] = (half_t)head_w[i];
  if (i < CC * CKK) {
    int c = i >> 6, k = i & 63;
    half_t v = (half_t)mu[i];               // mu is (C,K) row-major
    for (int b = 0; b < CB; ++b) {
      muT[(long)b * CKK * CC + (long)k * CC + c] = v;
      muck[(long)b * CC * CKK + i] = v;
    }
  }
}

// ---------------------------------------------------------------------------
// Stem GEMM fused with x-transpose: Yf[m][o] = sum_c x[b][c][n]*W[o][c]+bias,
// m = b*4096+n.  A-tile (64c x 128n) reg-staged from fp32 x, converted and
// ds_written transposed into the same XOR-swizzled LDS layout as v4.
// Writes Yf (M,512) row-major and ycn (B,512,4096).
template <bool SWZ>
__global__ __launch_bounds__(256) void gemm_stem(
    const float* __restrict__ X, const half_t* __restrict__ Bw,
    const float* __restrict__ bias,
    half_t* __restrict__ Co, half_t* __restrict__ CoT)
{
  constexpr int SAB = 16384;                    // halfs per dbuf set (A+B)
  __shared__ __align__(16) half_t smem[2 * SAB];   // 64 KiB (epi reuses)
  const int tid = threadIdx.x, wid = tid >> 6, lane = tid & 63;
  int bid = blockIdx.x;
  if constexpr (SWZ) bid = swz8(bid, gridDim.x);
  const int tm = bid >> 2, tn = bid & 3;        // 512 m-tiles x 4 n-tiles
  const long row0 = (long)tm * 128;
  const long b = row0 >> 12;
  const int n0 = (int)(row0 & 4095);
  const float* Xb = X + b * ((long)CC * CN) + n0;
  const half_t* Bb = Bw + (long)tn * 128 * CC;
  const int wr = wid >> 1, wc = wid & 1;

  // A staging: thread covers n = tid&127, c = (tid>>7)*32 + e (e<32).
  const int an = tid & 127;
  const int ac0 = (tid >> 7) * 32;              // 0 or 32
  const int r8 = lane >> 3;
  const int gcs = ((lane & 7) ^ r8) * 8;        // B pre-swizzled source col

  float va[32];
  auto issueA = [&](int ks) {
    const float* p = Xb + (long)(ks * 64 + ac0) * CN + an;
#pragma unroll
    for (int e = 0; e < 32; ++e) va[e] = p[(long)e * CN];
  };
  auto writeA = [&](int buf) {
    half_t* dA = smem + buf * SAB;
#pragma unroll
    for (int g = 0; g < 4; ++g) {
      half8 h;
#pragma unroll
      for (int e = 0; e < 8; ++e) h[e] = (half_t)va[g * 8 + e];
      const int chunk = (ac0 >> 3) + g;         // 0..7
      *(half8*)&dA[an * 64 + ((chunk ^ (an & 7)) << 3)] = h;
    }
  };
  auto stageB = [&](int ks, int buf) {
    half_t* dB = smem + buf * SAB + 8192;
    const half_t* gb = Bb + (long)ks * 64;
#pragma unroll
    for (int c = wid; c < 16; c += 4)
      GLD_LDS(gb + (long)(c * 8 + r8) * CC + gcs, &dB[c * 512]);
  };

  f32x4 acc[4][4];
#pragma unroll
  for (int i = 0; i < 4; ++i)
#pragma unroll
    for (int j = 0; j < 4; ++j) acc[i][j] = f32x4{0.f, 0.f, 0.f, 0.f};

  issueA(0);
  stageB(0, 0);
  vmwait<0>();
  writeA(0);
  LGKM0;
  RAWBAR;

  int cur = 0;
  for (int ks = 0; ks < 8; ++ks) {
    if (ks < 7) { issueA(ks + 1); stageB(ks + 1, cur ^ 1); }
    const half_t* lA = smem + cur * SAB;
    const half_t* lB = lA + 8192;
#pragma unroll
    for (int kk = 0; kk < 2; ++kk) {
      half8 af[4], bfr[4];
      const int cg = kk * 4 + (lane >> 4);
#pragma unroll
      for (int i = 0; i < 4; ++i) {
        const int rA = wr * 64 + i * 16 + (lane & 15);
        af[i] = *(const half8*)&lA[rA * 64 + ((cg ^ (rA & 7)) << 3)];
      }
#pragma unroll
      for (int j = 0; j < 4; ++j) {
        const int rB = wc * 64 + j * 16 + (lane & 15);
        bfr[j] = *(const half8*)&lB[rB * 64 + ((cg ^ (rB & 7)) << 3)];
      }
      __builtin_amdgcn_s_setprio(1);
#pragma unroll
      for (int i = 0; i < 4; ++i)
#pragma unroll
        for (int j = 0; j < 4; ++j)
          acc[i][j] = __builtin_amdgcn_mfma_f32_16x16x32_f16(af[i], bfr[j],
                                                             acc[i][j], 0, 0, 0);
      __builtin_amdgcn_s_setprio(0);
    }
    RAWBAR;                       // all waves done reading buf[cur]
    if (ks < 7) {
      vmwait<0>();                // A regs + B lds arrived
      writeA(cur ^ 1);
      LGKM0;
    }
    RAWBAR;                       // buf[cur^1] fully ready
    cur ^= 1;
  }

  // Epilogue: ep[n-of-tile (o)][m], pitch 132, dual-layout wide stores.
  constexpr int PIT = 132;
  half_t* ep = smem;
#pragma unroll
  for (int j = 0; j < 4; ++j) {
    const int nl = wc * 64 + j * 16 + (lane & 15);
    const float bv = bias[tn * 128 + nl];
#pragma unroll
    for (int i = 0; i < 4; ++i) {
      const int ml = wr * 64 + i * 16 + ((lane >> 4) << 2);
      half4 h;
#pragma unroll
      for (int r = 0; r < 4; ++r) h[r] = (half_t)(acc[i][j][r] + bv);
      *(half4*)&ep[nl * PIT + ml] = h;
    }
  }
  __syncthreads();
  { // Yf row-major (m, o-contig)
#pragma unroll
    for (int s = 0; s < 8; ++s) {
      const int q = tid + 256 * s;
      const int m = q & 127, cc8 = q >> 7;
      half8 v;
#pragma unroll
      for (int e = 0; e < 8; ++e) v[e] = ep[(cc8 * 8 + e) * PIT + m];
      *(half8*)&Co[(row0 + m) * CC + tn * 128 + cc8 * 8] = v;
    }
  }
  { // ycn (B, o, 4096)
#pragma unroll
    for (int s = 0; s < 8; ++s) {
      const int q = tid + 256 * s;
      const int mc = q & 15, cl = q >> 4;
      half8 v = *(const half8*)&ep[cl * PIT + mc * 8];
      *(half8*)&CoT[(b * CC + tn * 128 + cl) * CN + n0 + mc * 8] = v;
    }
  }
}

// ---------------------------------------------------------------------------
// Generic fp16 GEMM, A@B^T form (v4 pipeline): counted-vmcnt dbuf + swizzle.
// MODE bit0: +bias; bit1: relu; bit2: atomic fp32 accumulate into Cacc.
// EPI bit0: LDS epilogue row-major. EPI bit1: transposed (B, Nn, 4096).
template <int BM, int BN, int MODE, int EPI, bool SWZ>
__global__ __launch_bounds__(256) void gemm_abt(
    const half_t* __restrict__ A, const half_t* __restrict__ Bm,
    half_t* __restrict__ Co, half_t* __restrict__ CoT,
    float* __restrict__ Cacc, const float* __restrict__ bias,
    int M, int Nn, int Kk, int ksplit, long sA, long sB, long sC)
{
  constexpr int FM = BM / 32, FN = BN / 32;
  constexpr int HB = (BM + BN) * 64;
  constexpr int LCNT = (BM / 8) / 4 + (BN / 8) / 4;
  constexpr int STG = 2 * HB;
  constexpr int EPS = (EPI != 0) ? BN * (BM + 4) : 0;
  constexpr int TOT = STG > EPS ? STG : EPS;
  __shared__ __align__(16) half_t smem[TOT];

  const int tid = threadIdx.x, wid = tid >> 6, lane = tid & 63;
  int bid = blockIdx.x;
  if constexpr (SWZ) bid = swz8(bid, gridDim.x);
  const int tilesN = Nn / BN;
  const int tm = bid / tilesN, tn = bid % tilesN;
  const long bz = blockIdx.z;
  const half_t* Ab = A + bz * sA + (long)tm * BM * Kk;
  const half_t* Bb = Bm + bz * sB + (long)tn * BN * Kk;
  const int ksteps = Kk >> 6;
  const int per = ksteps / ksplit;
  const int ks0 = blockIdx.y * per, ks1 = ks0 + per;
  const int wr = wid >> 1, wc = wid & 1;

  const int r8 = lane >> 3;
  const int gcs = ((lane & 7) ^ r8) * 8;

  auto stage = [&](int ks, int buf) {
    half_t* dA = smem + buf * HB;
    half_t* dB = dA + BM * 64;
    const half_t* ga = Ab + (long)ks * 64;
#pragma unroll
    for (int c = wid; c < BM / 8; c += 4)
      GLD_LDS(ga + (long)(c * 8 + r8) * Kk + gcs, &dA[c * 512]);
    const half_t* gb = Bb + (long)ks * 64;
#pragma unroll
    for (int c = wid; c < BN / 8; c += 4)
      GLD_LDS(gb + (long)(c * 8 + r8) * Kk + gcs, &dB[c * 512]);
  };

  f32x4 acc[FM][FN];
#pragma unroll
  for (int i = 0; i < FM; ++i)
#pragma unroll
    for (int j = 0; j < FN; ++j) acc[i][j] = f32x4{0.f, 0.f, 0.f, 0.f};

  stage(ks0, 0);
  if (ks0 + 1 < ks1) { stage(ks0 + 1, 1); vmwait<LCNT>(); }
  else               { vmwait<0>(); }
  RAWBAR;

  int cur = 0;
  for (int ks = ks0; ks < ks1; ++ks) {
    const half_t* lA = smem + cur * HB;
    const half_t* lB = lA + BM * 64;
#pragma unroll
    for (int kk = 0; kk < 2; ++kk) {
      half8 af[FM], bfr[FN];
      const int cg = kk * 4 + (lane >> 4);
#pragma unroll
      for (int i = 0; i < FM; ++i) {
        const int rA = wr * (BM / 2) + i * 16 + (lane & 15);
        af[i] = *(const half8*)&lA[rA * 64 + ((cg ^ (rA & 7)) << 3)];
      }
#pragma unroll
      for (int j = 0; j < FN; ++j) {
        const int rB = wc * (BN / 2) + j * 16 + (lane & 15);
        bfr[j] = *(const half8*)&lB[rB * 64 + ((cg ^ (rB & 7)) << 3)];
      }
      __builtin_amdgcn_s_setprio(1);
#pragma unroll
      for (int i = 0; i < FM; ++i)
#pragma unroll
        for (int j = 0; j < FN; ++j)
          acc[i][j] = __builtin_amdgcn_mfma_f32_16x16x32_f16(af[i], bfr[j],
                                                             acc[i][j], 0, 0, 0);
      __builtin_amdgcn_s_setprio(0);
    }
    RAWBAR;
    const bool more = (ks + 2 < ks1);
    if (more) { stage(ks + 2, cur); vmwait<LCNT>(); }
    else      { vmwait<0>(); }
    RAWBAR;
    cur ^= 1;
  }

  if constexpr (EPI != 0) {
    static_assert(BM == 128 && BN == 128, "LDS epilogue assumes 128x128");
    constexpr int PIT = BM + 4;
    half_t* ep = smem;
#pragma unroll
    for (int j = 0; j < FN; ++j) {
      const int nl = wc * 64 + j * 16 + (lane & 15);
      float bv = 0.f;
      if constexpr (MODE & 1) bv = bias[tn * BN + nl];
#pragma unroll
      for (int i = 0; i < FM; ++i) {
        const int ml = wr * 64 + i * 16 + ((lane >> 4) << 2);
        half4 h;
#pragma unroll
        for (int r = 0; r < 4; ++r) {
          float v = acc[i][j][r] + bv;
          if constexpr (MODE & 2) v = fmaxf(v, 0.f);
          h[r] = (half_t)v;
        }
        *(half4*)&ep[nl * PIT + ml] = h;
      }
    }
    __syncthreads();
    const long rowbase = (long)tm * BM;
    if constexpr (EPI & 1) {
#pragma unroll
      for (int s = 0; s < 8; ++s) {
        const int q = tid + 256 * s;
        const int m = q & 127, cc8 = q >> 7;
        half8 v;
#pragma unroll
        for (int e = 0; e < 8; ++e) v[e] = ep[(cc8 * 8 + e) * PIT + m];
        *(half8*)&Co[bz * sC + (rowbase + m) * Nn + tn * BN + cc8 * 8] = v;
      }
    }
    if constexpr (EPI & 2) {
      const long b = rowbase >> 12, nbase = rowbase & 4095;
#pragma unroll
      for (int s = 0; s < 8; ++s) {
        const int q = tid + 256 * s;
        const int mc = q & 15, cl = q >> 4;
        half8 v = *(const half8*)&ep[cl * PIT + mc * 8];
        *(half8*)&CoT[(b * Nn + tn * BN + cl) * 4096 + nbase + mc * 8] = v;
      }
    }
  } else {
#pragma unroll
    for (int j = 0; j < FN; ++j) {
      const int n = tn * BN + wc * (BN / 2) + j * 16 + (lane & 15);
      float bv = 0.f;
      if constexpr (MODE & 1) bv = bias[n];
#pragma unroll
      for (int i = 0; i < FM; ++i) {
        const int mbase = tm * BM + wr * (BM / 2) + i * 16 + ((lane >> 4) << 2);
#pragma unroll
        for (int r = 0; r < 4; ++r) {
          const long idx = bz * sC + (long)(mbase + r) * Nn + n;
          if constexpr ((MODE & 4) != 0) {
            atomicAdd(&Cacc[idx], acc[i][j][r]);
          } else {
            float v = acc[i][j][r] + bv;
            if constexpr ((MODE & 2) != 0) v = fmaxf(v, 0.f);
            Co[idx] = (half_t)v;
          }
        }
      }
    }
  }
}

// ---------------------------------------------------------------------------
// K3: S = Yf @ muT^T (128 rows x 64 cols per block), in-register rowwise
// softmax, writes zT (K,N) always, z (N,K) when zp != nullptr (final iter).
__global__ __launch_bounds__(256) void s_softmax(
    const half_t* __restrict__ Yf, const half_t* __restrict__ muT,
    half_t* __restrict__ zp, half_t* __restrict__ zT)
{
  constexpr int HB = (128 + 64) * 64;     // halfs per staging buffer
  __shared__ __align__(16) union {
    half_t st[2 * HB];                    // 48 KiB staging (dbuf)
    half_t zh[128 * 68];                  // epilogue z tile
  } sm;
  const int tid = threadIdx.x, wid = tid >> 6, lane = tid & 63;
  const int tm = blockIdx.x;
  const long bz = blockIdx.z;
  const half_t* Ab = Yf + bz * (long)CN * CC + (long)tm * 128 * CC;
  const half_t* Bb = muT + bz * (long)CKK * CC;

  const int r8 = lane >> 3;
  const int gcs = ((lane & 7) ^ r8) * 8;

  auto stage = [&](int ks, int buf) {
    half_t* dA = sm.st + buf * HB;
    half_t* dB = dA + 128 * 64;
    const half_t* ga = Ab + (long)ks * 64;
#pragma unroll
    for (int c = wid; c < 16; c += 4)
      GLD_LDS(ga + (long)(c * 8 + r8) * CC + gcs, &dA[c * 512]);
    const half_t* gb = Bb + (long)ks * 64;
#pragma unroll
    for (int c = wid; c < 8; c += 4)
      GLD_LDS(gb + (long)(c * 8 + r8) * CC + gcs, &dB[c * 512]);
  };

  f32x4 acc[2][4];
#pragma unroll
  for (int i = 0; i < 2; ++i)
#pragma unroll
    for (int j = 0; j < 4; ++j) acc[i][j] = f32x4{0.f, 0.f, 0.f, 0.f};

  stage(0, 0);
  stage(1, 1);
  vmwait<6>();
  RAWBAR;
  int cur = 0;
  for (int ks = 0; ks < 8; ++ks) {   // Kk = 512
    const half_t* lA = sm.st + cur * HB;
    const half_t* lB = lA + 128 * 64;
#pragma unroll
    for (int kk = 0; kk < 2; ++kk) {
      half8 af[2], bfr[4];
      const int cg = kk * 4 + (lane >> 4);
#pragma unroll
      for (int i = 0; i < 2; ++i) {
        const int rA = wid * 32 + i * 16 + (lane & 15);
        af[i] = *(const half8*)&lA[rA * 64 + ((cg ^ (rA & 7)) << 3)];
      }
#pragma unroll
      for (int j = 0; j < 4; ++j) {
        const int rB = j * 16 + (lane & 15);
        bfr[j] = *(const half8*)&lB[rB * 64 + ((cg ^ (rB & 7)) << 3)];
      }
      __builtin_amdgcn_s_setprio(1);
#pragma unroll
      for (int i = 0; i < 2; ++i)
#pragma unroll
        for (int j = 0; j < 4; ++j)
          acc[i][j] = __builtin_amdgcn_mfma_f32_16x16x32_f16(af[i], bfr[j],
                                                             acc[i][j], 0, 0, 0);
      __builtin_amdgcn_s_setprio(0);
    }
    RAWBAR;
    const bool more = (ks + 2 < 8);
    if (more) { stage(ks + 2, cur); vmwait<6>(); }
    else      { vmwait<0>(); }
    RAWBAR;
    cur ^= 1;
  }

  // In-register softmax over 64 cols per row.
#pragma unroll
  for (int i = 0; i < 2; ++i)
#pragma unroll
    for (int r = 0; r < 4; ++r) {
      float mx = fmaxf(fmaxf(acc[i][0][r], acc[i][1][r]),
                       fmaxf(acc[i][2][r], acc[i][3][r]));
#pragma unroll
      for (int m = 1; m < 16; m <<= 1) mx = fmaxf(mx, __shfl_xor(mx, m));
      float p[4], s = 0.f;
#pragma unroll
      for (int j = 0; j < 4; ++j) { p[j] = __expf(acc[i][j][r] - mx); s += p[j]; }
#pragma unroll
      for (int m = 1; m < 16; m <<= 1) s += __shfl_xor(s, m);
      const float inv = 1.f / s;
#pragma unroll
      for (int j = 0; j < 4; ++j) acc[i][j][r] = p[j] * inv;
    }

#pragma unroll
  for (int i = 0; i < 2; ++i)
#pragma unroll
    for (int j = 0; j < 4; ++j)
#pragma unroll
      for (int r = 0; r < 4; ++r) {
        const int row = wid * 32 + i * 16 + ((lane >> 4) << 2) + r;
        const int col = j * 16 + (lane & 15);
        sm.zh[row * 68 + col] = (half_t)acc[i][j][r];
      }
  __syncthreads();
  if (zp) { // z (N,K): rows n, contiguous k  (final iter only)
    const int nl = tid >> 1, seg = tid & 1;
    const long base = bz * (long)CN * CKK + (long)(tm * 128 + nl) * CKK + seg * 32;
#pragma unroll
    for (int g = 0; g < 4; ++g) {
      half8 v;
#pragma unroll
      for (int e = 0; e < 8; ++e) v[e] = sm.zh[nl * 68 + seg * 32 + g * 8 + e];
      *(half8*)&zp[base + g * 8] = v;
    }
  }
  { // zT (K,N): rows k, contiguous n
    const int k = tid >> 2, seg = tid & 3;
    const long base = bz * (long)CKK * CN + (long)k * CN + tm * 128 + seg * 32;
#pragma unroll
    for (int g = 0; g < 4; ++g) {
      half8 v;
#pragma unroll
      for (int e = 0; e < 8; ++e) v[e] = sm.zh[(seg * 32 + g * 8 + e) * 68 + k];
      *(half8*)&zT[base + g * 8] = v;
    }
  }
}

// ---------------------------------------------------------------------------
// mu = R / max(||R||_c, 1e-12) per (b,k); write muT (K,C) and mu_ck (C,K).
__global__ __launch_bounds__(64) void mu_norm(
    const float* __restrict__ acc, half_t* __restrict__ muT, half_t* __restrict__ muck)
{
  const int bk = blockIdx.x;           // b*64 + k
  const int b = bk >> 6, k = bk & 63;
  const float* row = acc + (long)bk * CC;
  const int t = threadIdx.x;
  float v[8]; float s = 0.f;
#pragma unroll
  for (int e = 0; e < 8; ++e) { v[e] = row[t * 8 + e]; s += v[e] * v[e]; }
#pragma unroll
  for (int m = 1; m < 64; m <<= 1) s += __shfl_xor(s, m);
  const float inv = 1.f / fmaxf(sqrtf(s), 1e-12f);
  half8 o;
#pragma unroll
  for (int e = 0; e < 8; ++e) o[e] = (half_t)(v[e] * inv);
  *(half8*)&muT[(long)bk * CC + t * 8] = o;
  half_t* mc = muck + (long)b * CC * CKK;
#pragma unroll
  for (int e = 0; e < 8; ++e) mc[(long)(t * 8 + e) * CKK + k] = o[e];
}

// ---------------------------------------------------------------------------
// BN stats from hcn (B,C,N): one block per channel, no atomics.
__global__ __launch_bounds__(256) void bn_stats2(
    const half_t* __restrict__ hcn, float* __restrict__ stats)
{
  const int c = blockIdx.x, tid = threadIdx.x;
  float s = 0.f, s2 = 0.f;
  for (int b = 0; b < CB; ++b) {
    const half_t* p = hcn + ((long)b * CC + c) * CN;
    for (int i = tid * 8; i < CN; i += 2048) {
      half8 v = *(const half8*)&p[i];
#pragma unroll
      for (int e = 0; e < 8; ++e) { float f = (float)v[e]; s += f; s2 += f * f; }
    }
  }
#pragma unroll
  for (int m = 1; m < 64; m <<= 1) { s += __shfl_xor(s, m); s2 += __shfl_xor(s2, m); }
  __shared__ float r[8];
  const int wid = tid >> 6;
  if ((tid & 63) == 0) { r[wid] = s; r[4 + wid] = s2; }
  __syncthreads();
  if (tid == 0) {
    stats[c] = r[0] + r[1] + r[2] + r[3];
    stats[CC + c] = r[4] + r[5] + r[6] + r[7];
  }
}

__global__ void bn_param(const float* __restrict__ stats,
                         const float* __restrict__ gamma, const float* __restrict__ beta,
                         float* __restrict__ scsh)
{
  const int c = threadIdx.x;
  const float cnt = 1.f / 65536.f;
  const float mean = stats[c] * cnt;
  const float var = stats[CC + c] * cnt - mean * mean;
  const float sc = gamma[c] * rsqrtf(var + 1e-5f);
  scsh[c] = sc;
  scsh[CC + c] = beta[c] - mean * sc;
}

// ---------------------------------------------------------------------------
// out(B,C,N) = relu( hcn*sc + sh + x ), pure elementwise (hcn already (C,N)).
__global__ __launch_bounds__(256) void bn_final2(
    const half_t* __restrict__ hcn, const float* __restrict__ x,
    const float* __restrict__ scsh, float* __restrict__ out)
{
  const long i8 = (long)blockIdx.x * 256 + threadIdx.x;   // 8-elem chunk id
  const int c = (int)((i8 >> 9) & 511);
  const float sc = scsh[c], sh = scsh[CC + c];
  half8 h = *(const half8*)&hcn[i8 * 8];
  f32x4 x0 = *(const f32x4*)&x[i8 * 8];
  f32x4 x1 = *(const f32x4*)&x[i8 * 8 + 4];
  f32x4 o0, o1;
#pragma unroll
  for (int e = 0; e < 4; ++e) o0[e] = fmaxf((float)h[e] * sc + sh + x0[e], 0.f);
#pragma unroll
  for (int e = 0; e < 4; ++e) o1[e] = fmaxf((float)h[4 + e] * sc + sh + x1[e], 0.f);
  *(f32x4*)&out[i8 * 8] = o0;
  *(f32x4*)&out[i8 * 8 + 4] = o1;
}

// ---------------------------------------------------------------------------
extern "C" void kernel_launch(void* const* d_in, const int* in_sizes, int n_in,
                              void* d_out, int out_size, void* d_ws, size_t ws_size,
                              hipStream_t stream)
{
  const float* x      = (const float*)d_in[0];
  const float* mu     = (const float*)d_in[1];
  const float* stem_w = (const float*)d_in[2];
  const float* stem_b = (const float*)d_in[3];
  const float* head_w = (const float*)d_in[4];
  const float* head_b = (const float*)d_in[5];
  const float* bn_g   = (const float*)d_in[6];
  const float* bn_b   = (const float*)d_in[7];
  float* out = (float*)d_out;

  const size_t NEED = 214ull << 20;
  if (ws_size < NEED) {
    hipMemsetAsync(d_out, 0, (size_t)out_size * 4, stream);
    return;
  }
  char* ws = (char*)d_ws;
  const long MB = 1 << 20;
  half_t* y2f  = (half_t*)(ws);              // 64 MiB (was xT; now y2 output)
  half_t* Yf   = (half_t*)(ws + 64 * MB);    // 64 MiB ; reused as hcn
  half_t* ycn  = (half_t*)(ws + 128 * MB);   // 64 MiB
  half_t* z    = (half_t*)(ws + 192 * MB);   // 8 MiB
  half_t* zT   = (half_t*)(ws + 200 * MB);   // 8 MiB
  half_t* muT  = (half_t*)(ws + 208 * MB);   // 1 MiB
  half_t* muck = (half_t*)(ws + 209 * MB);   // 1 MiB
  float* muacc = (float*)(ws + 210 * MB);    // 2 MiB
  half_t* swh  = (half_t*)(ws + 212 * MB);
  half_t* hwh  = (half_t*)(ws + 212 * MB + 512 * 1024);
  float* stats = (float*)(ws + 213 * MB);
  float* scsh  = (float*)(ws + 213 * MB + 8 * 1024);
  half_t* hcn = Yf;    // Yf dead after final softmax

  prep<<<1024, 256, 0, stream>>>(stem_w, head_w, mu, swh, hwh, muT, muck);
  // stem (fused x-transpose): Yf (B*N,C) + ycn (B,C,N) from fp32 x directly
  gemm_stem<true><<<2048, 256, 0, stream>>>(x, swh, stem_b, Yf, ycn);

  for (int it = 0; it < 3; ++it) {
    s_softmax<<<dim3(32, 1, 16), 256, 0, stream>>>(
        Yf, muT, (it == 2) ? z : nullptr, zT);
    hipMemsetAsync(muacc, 0, (size_t)CB * CKK * CC * 4, stream);
    // mu_raw^T (K,C) = zT @ ycn^T (reduction over n, split 4, fp32 atomics)
    gemm_abt<64, 128, 4, 0, false><<<dim3(4, 4, 16), 256, 0, stream>>>(
        zT, ycn, nullptr, nullptr, muacc, nullptr, CKK, CC, CN, 4,
        (long)CKK * CN, (long)CC * CN, (long)CKK * CC);
    mu_norm<<<CB * CKK, 64, 0, stream>>>(muacc, muT, muck);
  }
  // y2f (B,N,C) = relu(z @ mu_ck^T)
  gemm_abt<128, 128, 2, 1, true><<<dim3(128, 1, 16), 256, 0, stream>>>(
      z, muck, y2f, nullptr, nullptr, nullptr, CN, CC, CKK, 1,
      (long)CN * CKK, (long)CC * CKK, (long)CN * CC);
  // head: hcn (B,C,N) = (y2f @ head_w^T + head_b) transposed on store
  gemm_abt<128, 128, 1, 2, true><<<dim3(2048, 1, 1), 256, 0, stream>>>(
      y2f, hwh, nullptr, hcn, nullptr, head_b, (int)MALL, CC, CC, 1, 0, 0, 0);

  bn_stats2<<<CC, 256, 0, stream>>>(hcn, stats);
  bn_param<<<1, 512, 0, stream>>>(stats, bn_g, bn_b, scsh);
  bn_final2<<<16384, 256, 0, stream>>>(hcn, x, scsh, out);
}